// Round 3
// baseline (171.433 us; speedup 1.0000x reference)
//
#include <hip/hip_runtime.h>

#define B_  8
#define C_  256
#define L_  4096
#define KD_ 768   // 256 ci * 3 taps, kd = ci*3 + k

typedef __attribute__((ext_vector_type(8))) __bf16 bf16x8;
typedef __attribute__((ext_vector_type(4))) float f32x4;
typedef __attribute__((ext_vector_type(8))) unsigned short u16x8;

__device__ __forceinline__ unsigned short f2bf(float f){
  union { float f; unsigned u; } v; v.f = f;
  unsigned r = v.u + 0x7fffu + ((v.u >> 16) & 1u);   // RNE
  return (unsigned short)(r >> 16);
}
__device__ __forceinline__ float bf2f(unsigned short h){
  union { unsigned u; float f; } v; v.u = ((unsigned)h) << 16;
  return v.f;
}

// Swizzled u16 index in a [rows][128] u16 tile (row stride 256B).
// XOR col bits 3..5 with row bits 0..2: column ds_read_b128 goes 16-way -> ~2-way.
__device__ __forceinline__ int swz(int row, int col){
  return (row << 7) + (col ^ ((row & 7) << 3));
}

// async global->LDS: 32KB tile, 16B/lane, linear LDS dest (source is pre-swizzled).
__device__ __forceinline__ void stage_tile32k(const unsigned short* __restrict__ g,
                                              unsigned short* l, int t){
  int wid = t >> 6, lane = t & 63;
  #pragma unroll
  for (int s = 0; s < 4; ++s){
    int seg = wid * 4 + s;
    const char* src = (const char*)g + seg * 1024 + lane * 16;
    char* dst = (char*)l + seg * 1024;
    __builtin_amdgcn_global_load_lds(
        (const __attribute__((address_space(1))) unsigned int*)src,
        (__attribute__((address_space(3))) unsigned int*)dst, 16, 0, 0);
  }
}

// ---- prep: both weight tensors [256][768] -> bf16 swizzled tiles -------------
// layout: [rt(2)][ch(8)][swz(row 128, col 96 pad 128)]
__global__ __launch_bounds__(256) void prep_w(const float* __restrict__ offw,
                                              const float* __restrict__ w,
                                              unsigned short* __restrict__ wO,
                                              unsigned short* __restrict__ wM){
  int idx = blockIdx.x * 256 + threadIdx.x;     // 768 blocks * 256 = 196608 exact
  int r = idx / KD_, rem = idx % KD_;
  int rt = r >> 7, row = r & 127;
  int ch = rem / 96, col = rem % 96;
  int pos = (rt * 8 + ch) * 16384 + swz(row, col);
  wO[pos] = f2bf(offw[idx]);
  wM[pos] = f2bf(w[idx]);
}

// ---- unified GEMM: MODE 0 = offset conv (off==0, bf16 out), MODE 1 = deform --
// D[m][l] = sum_kd A[m][kd] * S[l][kd],  kd = ci*3+k,
// S[l][ci*3+k] = lerp(x[ci], (l-1+off)+k)  (MODE0: off=0 -> x[ci][l-1+k] exact)
template <int MODE>
__global__ __launch_bounds__(512, 2) void dconv_gemm(
    const float* __restrict__ x,
    const unsigned short* __restrict__ wT,
    const float* __restrict__ bvec,
    const unsigned short* __restrict__ off_in,
    void* __restrict__ outp){
  __shared__ __align__(16) unsigned short As[2][16384];
  __shared__ __align__(16) unsigned short Bs[2][16384];

  // XCD-aware swizzle: 512 blocks, 8 XCDs -> batch b pinned to one XCD
  int bid = blockIdx.x;
  int wk = (bid & 7) * 64 + (bid >> 3);
  int b  = wk >> 6;
  int yt = (wk >> 5) & 1;
  int lt = wk & 31;
  int l0 = lt * 128, m0 = yt * 128;

  int t = threadIdx.x, lane = t & 63, wid = t >> 6;
  int wm = wid >> 1, wn = wid & 1;               // wave tile: 32 m x 64 l
  const float* xb = x + (size_t)b * C_ * L_;
  const unsigned short* offp = off_in + (size_t)b * C_ * L_;
  const unsigned short* wBase = wT + (size_t)yt * 8 * 16384;
  f32x4 acc[2][4] = {};

  // sampling unit coords: wave covers 8 rows x 8 cols (conflict-free ds_write,
  // gathers sector-coalesced: 8 consecutive l per c-row)
  int cc_b = t & 7;
  int lr_b = ((t >> 3) & 7) + ((t >> 6) & 7) * 8;
  constexpr int NJ = MODE ? 4 : 3;

  // ---- prologue: stage chunk 0 (combined gather+write)
  stage_tile32k(wBase, As[0], t);
  #pragma unroll
  for (int it = 0; it < 8; ++it){
    int cc = cc_b + 8 * (it & 3);
    int lrow = lr_b + (it >> 2) * 64;
    int c = cc, l = l0 + lrow;
    int i0; float w1;
    if (MODE){
      float off = bf2f(offp[(size_t)c * L_ + l]);
      float pos = (float)(l - 1) + off;
      float p0  = floorf(pos);
      w1 = pos - p0; i0 = (int)p0;
    } else { i0 = l - 1; w1 = 0.f; }
    float v[NJ];
    #pragma unroll
    for (int j = 0; j < NJ; ++j){
      int ix = i0 + j;
      v[j] = (ix >= 0 && ix < L_) ? xb[(size_t)c * L_ + ix] : 0.f;
    }
    #pragma unroll
    for (int k = 0; k < 3; ++k){
      float s = MODE ? (v[k] * (1.f - w1) + v[k + 1] * w1) : v[k];
      Bs[0][swz(lrow, cc * 3 + k)] = f2bf(s);
    }
  }
  __syncthreads();

  // ---- 2-phase main loop: issue-early (gll + gathers), MFMA, write-late
  float gv[8][4]; float gw[8];
  for (int ch = 0; ch < 8; ++ch){
    int p = ch & 1;
    bool pre = (ch + 1 < 8);
    if (pre){
      stage_tile32k(wBase + (size_t)(ch + 1) * 16384, As[p ^ 1], t);
      int cin = (ch + 1) * 32;
      #pragma unroll
      for (int it = 0; it < 8; ++it){
        int cc = cc_b + 8 * (it & 3);
        int lrow = lr_b + (it >> 2) * 64;
        int c = cin + cc, l = l0 + lrow;
        int i0;
        if (MODE){
          float off = bf2f(offp[(size_t)c * L_ + l]);
          float pos = (float)(l - 1) + off;
          float p0  = floorf(pos);
          gw[it] = pos - p0; i0 = (int)p0;
        } else { i0 = l - 1; gw[it] = 0.f; }
        const float* xr = xb + (size_t)c * L_;
        #pragma unroll
        for (int j = 0; j < NJ; ++j){
          int ix = i0 + j;
          gv[it][j] = (ix >= 0 && ix < L_) ? xr[ix] : 0.f;
        }
      }
    }
    // MFMA on buffer p (ds_reads swizzled; no conflict after XOR)
    const unsigned short* Ap = As[p];
    const unsigned short* Bp = Bs[p];
    #pragma unroll
    for (int kf = 0; kf < 3; ++kf){
      int col = kf * 32 + (lane >> 4) * 8;
      bf16x8 af[2], bfv[4];
      #pragma unroll
      for (int mi = 0; mi < 2; ++mi)
        af[mi] = __builtin_bit_cast(bf16x8,
          *reinterpret_cast<const u16x8*>(&Ap[swz(wm * 32 + mi * 16 + (lane & 15), col)]));
      #pragma unroll
      for (int ni = 0; ni < 4; ++ni)
        bfv[ni] = __builtin_bit_cast(bf16x8,
          *reinterpret_cast<const u16x8*>(&Bp[swz(wn * 64 + ni * 16 + (lane & 15), col)]));
      #pragma unroll
      for (int mi = 0; mi < 2; ++mi)
        #pragma unroll
        for (int ni = 0; ni < 4; ++ni)
          acc[mi][ni] = __builtin_amdgcn_mfma_f32_16x16x32_bf16(af[mi], bfv[ni], acc[mi][ni], 0, 0, 0);
    }
    // write-late: convert + ds_write next Bs
    if (pre){
      unsigned short* Bn = Bs[p ^ 1];
      #pragma unroll
      for (int it = 0; it < 8; ++it){
        int cc = cc_b + 8 * (it & 3);
        int lrow = lr_b + (it >> 2) * 64;
        #pragma unroll
        for (int k = 0; k < 3; ++k){
          float s = MODE ? (gv[it][k] * (1.f - gw[it]) + gv[it][k + 1] * gw[it])
                         : gv[it][k];
          Bn[swz(lrow, cc * 3 + k)] = f2bf(s);
        }
      }
      __syncthreads();
    }
  }

  // ---- epilogue
  int rg = lane >> 4, cx = lane & 15;
  if (MODE == 0){
    unsigned short* ob = (unsigned short*)outp + (size_t)b * C_ * L_;
    #pragma unroll
    for (int mi = 0; mi < 2; ++mi)
      #pragma unroll
      for (int r = 0; r < 4; ++r){
        int c = m0 + wm * 32 + mi * 16 + rg * 4 + r;
        float bv = bvec[c];
        #pragma unroll
        for (int ni = 0; ni < 4; ++ni){
          int l = l0 + wn * 64 + ni * 16 + cx;
          ob[(size_t)c * L_ + l] = f2bf(acc[mi][ni][r] + bv);
        }
      }
  } else {
    float* ob = (float*)outp + (size_t)b * C_ * L_;
    #pragma unroll
    for (int mi = 0; mi < 2; ++mi)
      #pragma unroll
      for (int r = 0; r < 4; ++r){
        int o = m0 + wm * 32 + mi * 16 + rg * 4 + r;
        float bv = bvec[o];
        #pragma unroll
        for (int ni = 0; ni < 4; ++ni){
          int l = l0 + wn * 64 + ni * 16 + cx;
          ob[(size_t)o * L_ + l] = acc[mi][ni][r] + bv;
        }
      }
  }
}

extern "C" void kernel_launch(void* const* d_in, const int* in_sizes, int n_in,
                              void* d_out, int out_size, void* d_ws, size_t ws_size,
                              hipStream_t stream){
  (void)in_sizes; (void)n_in; (void)out_size; (void)ws_size;
  const float* x   = (const float*)d_in[0];
  const float* ow  = (const float*)d_in[1];
  const float* obv = (const float*)d_in[2];
  const float* w   = (const float*)d_in[3];
  const float* bv  = (const float*)d_in[4];
  float* out = (float*)d_out;

  unsigned short* wO     = (unsigned short*)d_ws;   // 2*8*16384 u16 = 512KB
  unsigned short* wM     = wO + 2 * 8 * 16384;      // 512KB
  unsigned short* off_ws = wM + 2 * 8 * 16384;      // 16MB bf16 off[b][c][l]

  prep_w<<<dim3(768), dim3(256), 0, stream>>>(ow, w, wO, wM);
  dconv_gemm<0><<<dim3(512), dim3(512), 0, stream>>>(x, wO, obv, off_ws, off_ws);
  dconv_gemm<1><<<dim3(512), dim3(512), 0, stream>>>(x, wM, bv, off_ws, out);
}